// Round 1
// baseline (722.126 us; speedup 1.0000x reference)
//
#include <hip/hip_runtime.h>
#include <hip/hip_bf16.h>

#define N_NODES 65536
#define D_IN 1024
#define D_HID 64
#define N_CLS 32

typedef short short8 __attribute__((ext_vector_type(8)));
typedef float floatx4 __attribute__((ext_vector_type(4)));

// ---------- degree count ----------
__global__ void k_count(const int* __restrict__ dst, int* __restrict__ cnt, int e) {
  int i = blockIdx.x * blockDim.x + threadIdx.x;
  if (i < e) atomicAdd(&cnt[dst[i]], 1);
}

// ---------- exclusive scan over 65536 counts (single block, 1024 threads) ----------
__global__ void k_scan(const int* __restrict__ cnt, int* __restrict__ rowptr,
                       int* __restrict__ cursor) {
  __shared__ int part[1024];
  int t = threadIdx.x;
  int base = t * 64;
  int s = 0;
  for (int i = 0; i < 64; i++) s += cnt[base + i];
  part[t] = s;
  __syncthreads();
  for (int off = 1; off < 1024; off <<= 1) {
    int v = (t >= off) ? part[t - off] : 0;
    __syncthreads();
    part[t] += v;
    __syncthreads();
  }
  int excl = (t == 0) ? 0 : part[t - 1];
  for (int i = 0; i < 64; i++) {
    rowptr[base + i] = excl;
    cursor[base + i] = excl;
    excl += cnt[base + i];
  }
  if (t == 1023) rowptr[N_NODES] = excl;
}

// ---------- rsqrt(deg), 1/deg ----------
__global__ void k_dinv(const int* __restrict__ cnt, float* __restrict__ dinv,
                       float* __restrict__ invdeg) {
  int i = blockIdx.x * blockDim.x + threadIdx.x;
  if (i < N_NODES) {
    float d = (float)(cnt[i] + 1);
    dinv[i] = rsqrtf(d);
    invdeg[i] = 1.0f / d;
  }
}

// ---------- CSR fill (src indices grouped by dst) ----------
__global__ void k_fill(const int* __restrict__ src, const int* __restrict__ dst,
                       int* __restrict__ cursor, int* __restrict__ csr_src, int e) {
  int i = blockIdx.x * blockDim.x + threadIdx.x;
  if (i < e) {
    int d = dst[i];
    int p = atomicAdd(&cursor[d], 1);
    csr_src[p] = src[i];
  }
}

// ---------- W1 -> W1^T in bf16 (row n = output channel, contiguous in k) ----------
__device__ __forceinline__ unsigned short f2bf(float f) {
  union { float f; unsigned u; } cv; cv.f = f;
  unsigned r = (cv.u + 0x7FFFu + ((cv.u >> 16) & 1u)) >> 16;
  return (unsigned short)r;
}

__global__ void k_w1t(const float* __restrict__ w1, unsigned short* __restrict__ w1t) {
  int i = blockIdx.x * blockDim.x + threadIdx.x;
  if (i < D_IN * D_HID) {
    int k = i / D_HID, n = i % D_HID;
    w1t[n * D_IN + k] = f2bf(w1[i]);
  }
}

// ---------- GEMM1: xw1[N,64] = x[N,1024] @ W1, bf16 MFMA ----------
// Block = 4 waves; each wave computes a 16-row x 64-col tile.
__global__ __launch_bounds__(256) void k_gemm1(const float* __restrict__ x,
    const unsigned short* __restrict__ w1t, float* __restrict__ xw1) {
  int wave = threadIdx.x >> 6;
  int lane = threadIdx.x & 63;
  int quad = lane >> 4;
  int l16 = lane & 15;
  int rowbase = blockIdx.x * 64 + wave * 16;
  const float* xrow = x + (size_t)(rowbase + l16) * D_IN + quad * 8;
  floatx4 acc[4];
#pragma unroll
  for (int nt = 0; nt < 4; nt++) acc[nt] = (floatx4){0.f, 0.f, 0.f, 0.f};
  const unsigned short* bbase = w1t + quad * 8;
  for (int k0 = 0; k0 < D_IN; k0 += 32) {
    float4 a01 = *(const float4*)(xrow + k0);
    float4 a23 = *(const float4*)(xrow + k0 + 4);
    float av[8] = {a01.x, a01.y, a01.z, a01.w, a23.x, a23.y, a23.z, a23.w};
    short8 afrag;
#pragma unroll
    for (int j = 0; j < 8; j++) afrag[j] = (short)f2bf(av[j]);
#pragma unroll
    for (int nt = 0; nt < 4; nt++) {
      short8 bfrag = *(const short8*)(bbase + (size_t)(nt * 16 + l16) * D_IN + k0);
      acc[nt] = __builtin_amdgcn_mfma_f32_16x16x32_bf16(afrag, bfrag, acc[nt], 0, 0, 0);
    }
  }
#pragma unroll
  for (int nt = 0; nt < 4; nt++)
#pragma unroll
    for (int r = 0; r < 4; r++)
      xw1[(size_t)(rowbase + quad * 4 + r) * D_HID + nt * 16 + l16] = acc[nt][r];
}

// ---------- agg1 fused: h = relu(sum_nbr(norm*xw1[src]) + xw1[i]/deg + b1) ----------
// One wave per node, lane = feature.
__global__ __launch_bounds__(256) void k_agg1(const float* __restrict__ xw1,
    const int* __restrict__ rowptr, const int* __restrict__ csr_src,
    const float* __restrict__ dinv, const float* __restrict__ invdeg,
    const float* __restrict__ b1, float* __restrict__ h) {
  int node = blockIdx.x * 4 + (threadIdx.x >> 6);
  int lane = threadIdx.x & 63;
  float acc = xw1[(size_t)node * D_HID + lane] * invdeg[node];
  float dd = dinv[node];
  int beg = rowptr[node], end = rowptr[node + 1];
  for (int e = beg; e < end; e++) {
    int s = csr_src[e];
    acc += xw1[(size_t)s * D_HID + lane] * (dinv[s] * dd);
  }
  float v = acc + b1[lane];
  h[(size_t)node * D_HID + lane] = v > 0.f ? v : 0.f;
}

// ---------- GEMM2: xw2[N,32] = h[N,64] @ W2[64,32], fp32 scalar ----------
__global__ __launch_bounds__(256) void k_gemm2(const float* __restrict__ h,
    const float* __restrict__ w2, float* __restrict__ xw2) {
  __shared__ float w2s[D_HID * N_CLS];
  for (int i = threadIdx.x; i < D_HID * N_CLS; i += 256) w2s[i] = w2[i];
  __syncthreads();
  int idx = blockIdx.x * 256 + threadIdx.x;
  int node = idx >> 5;
  int c = idx & 31;
  const float* hrow = h + (size_t)node * D_HID;
  float acc = 0.f;
#pragma unroll
  for (int k = 0; k < D_HID; k++) acc += hrow[k] * w2s[k * N_CLS + c];
  xw2[idx] = acc;
}

// ---------- agg2 fused: logits = agg + self + b2 ; out = log_softmax ----------
// One wave per node; half-waves split the edge list, lanes&31 = class.
__global__ __launch_bounds__(256) void k_agg2(const float* __restrict__ xw2,
    const int* __restrict__ rowptr, const int* __restrict__ csr_src,
    const float* __restrict__ dinv, const float* __restrict__ invdeg,
    const float* __restrict__ b2, float* __restrict__ out) {
  int node = blockIdx.x * 4 + (threadIdx.x >> 6);
  int lane = threadIdx.x & 63;
  int c = lane & 31;
  float dd = dinv[node];
  int beg = rowptr[node], end = rowptr[node + 1];
  float acc = 0.f;
  for (int e = beg + (lane >> 5); e < end; e += 2) {
    int s = csr_src[e];
    acc += xw2[(size_t)s * N_CLS + c] * (dinv[s] * dd);
  }
  acc += __shfl_down(acc, 32);
  if (lane < 32) {
    acc += xw2[(size_t)node * N_CLS + c] * invdeg[node];
    float logit = acc + b2[c];
    float m = logit;
#pragma unroll
    for (int o = 16; o > 0; o >>= 1) m = fmaxf(m, __shfl_xor(m, o, 32));
    float ex = __expf(logit - m);
    float ssum = ex;
#pragma unroll
    for (int o = 16; o > 0; o >>= 1) ssum += __shfl_xor(ssum, o, 32);
    out[(size_t)node * N_CLS + c] = logit - m - __logf(ssum);
  }
}

extern "C" void kernel_launch(void* const* d_in, const int* in_sizes, int n_in,
                              void* d_out, int out_size, void* d_ws, size_t ws_size,
                              hipStream_t stream) {
  (void)n_in; (void)out_size; (void)ws_size;
  const float* x  = (const float*)d_in[0];
  const int*   ei = (const int*)d_in[1];
  const float* w1 = (const float*)d_in[2];
  const float* b1 = (const float*)d_in[3];
  const float* w2 = (const float*)d_in[4];
  const float* b2 = (const float*)d_in[5];
  float* out = (float*)d_out;
  int e = in_sizes[1] / 2;
  const int* src = ei;
  const int* dst = ei + e;

  char* ws = (char*)d_ws;
  int* cnt            = (int*)(ws + 0x000000);            // 256KB
  int* rowptr         = (int*)(ws + 0x040000);            // 256KB (+1 entry pads into gap)
  int* cursor         = (int*)(ws + 0x0C0000);            // 256KB
  float* dinv         = (float*)(ws + 0x100000);          // 256KB
  float* invdeg       = (float*)(ws + 0x140000);          // 256KB
  int* csr_src        = (int*)(ws + 0x180000);            // 4MB (E ints)
  unsigned short* w1t = (unsigned short*)(ws + 0x580000); // 128KB
  float* xw1          = (float*)(ws + 0x600000);          // 16MB
  float* h            = (float*)(ws + 0x1600000);         // 16MB
  float* xw2          = xw1;                               // reuse: xw1 dead after agg1

  hipMemsetAsync(cnt, 0, N_NODES * sizeof(int), stream);
  k_count<<<(e + 255) / 256, 256, 0, stream>>>(dst, cnt, e);
  k_scan <<<1, 1024, 0, stream>>>(cnt, rowptr, cursor);
  k_dinv <<<N_NODES / 256, 256, 0, stream>>>(cnt, dinv, invdeg);
  k_fill <<<(e + 255) / 256, 256, 0, stream>>>(src, dst, cursor, csr_src, e);
  k_w1t  <<<(D_IN * D_HID) / 256, 256, 0, stream>>>(w1, w1t);
  k_gemm1<<<N_NODES / 64, 256, 0, stream>>>(x, w1t, xw1);
  k_agg1 <<<N_NODES / 4, 256, 0, stream>>>(xw1, rowptr, csr_src, dinv, invdeg, b1, h);
  k_gemm2<<<(N_NODES * N_CLS) / 256, 256, 0, stream>>>(h, w2, xw2);
  k_agg2 <<<N_NODES / 4, 256, 0, stream>>>(xw2, rowptr, csr_src, dinv, invdeg, b2, out);
}

// Round 3
// 611.345 us; speedup vs baseline: 1.1812x; 1.1812x over previous
//
#include <hip/hip_runtime.h>
#include <hip/hip_bf16.h>

#define N_NODES 65536
#define D_IN 1024
#define D_HID 64
#define N_CLS 32

typedef short short8 __attribute__((ext_vector_type(8)));
typedef float floatx4 __attribute__((ext_vector_type(4)));

// ---------- degree count (4 edges/thread, int4 loads) ----------
__global__ void k_count(const int* __restrict__ dst, int* __restrict__ cnt, int e4) {
  int i = blockIdx.x * blockDim.x + threadIdx.x;
  if (i < e4) {
    int4 d = ((const int4*)dst)[i];
    atomicAdd(&cnt[d.x], 1);
    atomicAdd(&cnt[d.y], 1);
    atomicAdd(&cnt[d.z], 1);
    atomicAdd(&cnt[d.w], 1);
  }
}

// ---------- rsqrt(deg) ----------
__global__ void k_dinv(const int* __restrict__ cnt, float* __restrict__ dinv) {
  int i = blockIdx.x * blockDim.x + threadIdx.x;
  if (i < N_NODES) dinv[i] = rsqrtf((float)(cnt[i] + 1));
}

// ---------- 3-phase scan: all coalesced, multi-block ----------
__global__ void k_scan_a(const int* __restrict__ cnt, int* __restrict__ bsum) {
  __shared__ int s[256];
  int t = threadIdx.x;
  s[t] = cnt[blockIdx.x * 256 + t];
  __syncthreads();
  for (int off = 128; off > 0; off >>= 1) {
    if (t < off) s[t] += s[t + off];
    __syncthreads();
  }
  if (t == 0) bsum[blockIdx.x] = s[0];
}

__global__ void k_scan_b(int* __restrict__ bsum, int* __restrict__ boff) {
  __shared__ int s[256];
  int t = threadIdx.x;
  int v = bsum[t];
  s[t] = v;
  __syncthreads();
  for (int off = 1; off < 256; off <<= 1) {
    int x = (t >= off) ? s[t - off] : 0;
    __syncthreads();
    s[t] += x;
    __syncthreads();
  }
  boff[t] = s[t] - v;  // exclusive
}

__global__ void k_scan_c(const int* __restrict__ cnt, const int* __restrict__ boff,
                         int* __restrict__ rowptr, int* __restrict__ cursor) {
  __shared__ int s[256];
  int t = threadIdx.x;
  int i = blockIdx.x * 256 + t;
  int v = cnt[i];
  s[t] = v;
  __syncthreads();
  for (int off = 1; off < 256; off <<= 1) {
    int x = (t >= off) ? s[t - off] : 0;
    __syncthreads();
    s[t] += x;
    __syncthreads();
  }
  int excl = s[t] - v + boff[blockIdx.x];
  rowptr[i] = excl;
  cursor[i] = excl;
  if (i == N_NODES - 1) rowptr[N_NODES] = excl + v;
}

// ---------- CSR fill (src grouped by dst), 4 edges/thread ----------
__global__ void k_fill(const int* __restrict__ src, const int* __restrict__ dst,
                       int* __restrict__ cursor, int* __restrict__ csr_src, int e4) {
  int i = blockIdx.x * blockDim.x + threadIdx.x;
  if (i < e4) {
    int4 d = ((const int4*)dst)[i];
    int4 s = ((const int4*)src)[i];
    csr_src[atomicAdd(&cursor[d.x], 1)] = s.x;
    csr_src[atomicAdd(&cursor[d.y], 1)] = s.y;
    csr_src[atomicAdd(&cursor[d.z], 1)] = s.z;
    csr_src[atomicAdd(&cursor[d.w], 1)] = s.w;
  }
}

// ---------- f32 -> bf16 round-to-nearest-even ----------
__device__ __forceinline__ unsigned short f2bf(float f) {
  union { float f; unsigned u; } cv; cv.f = f;
  unsigned r = (cv.u + 0x7FFFu + ((cv.u >> 16) & 1u)) >> 16;
  return (unsigned short)r;
}

__global__ void k_w1t(const float* __restrict__ w1, unsigned short* __restrict__ w1t) {
  int i = blockIdx.x * blockDim.x + threadIdx.x;
  if (i < D_IN * D_HID) {
    int k = i / D_HID, n = i % D_HID;
    w1t[n * D_IN + k] = f2bf(w1[i]);
  }
}

// ---------- GEMM1: xw1s[N,64] = dinv[i] * (x[N,1024] @ W1), bf16 MFMA ----------
__global__ __launch_bounds__(256) void k_gemm1(const float* __restrict__ x,
    const unsigned short* __restrict__ w1t, const float* __restrict__ dinv,
    float* __restrict__ xw1s) {
  int wave = threadIdx.x >> 6;
  int lane = threadIdx.x & 63;
  int quad = lane >> 4;
  int l16 = lane & 15;
  int rowbase = blockIdx.x * 64 + wave * 16;
  const float* xrow = x + (size_t)(rowbase + l16) * D_IN + quad * 8;
  floatx4 acc[4];
#pragma unroll
  for (int nt = 0; nt < 4; nt++) acc[nt] = (floatx4){0.f, 0.f, 0.f, 0.f};
  const unsigned short* bbase = w1t + quad * 8;
  for (int k0 = 0; k0 < D_IN; k0 += 32) {
    float4 a01 = *(const float4*)(xrow + k0);
    float4 a23 = *(const float4*)(xrow + k0 + 4);
    float av[8] = {a01.x, a01.y, a01.z, a01.w, a23.x, a23.y, a23.z, a23.w};
    short8 afrag;
#pragma unroll
    for (int j = 0; j < 8; j++) afrag[j] = (short)f2bf(av[j]);
#pragma unroll
    for (int nt = 0; nt < 4; nt++) {
      short8 bfrag = *(const short8*)(bbase + (size_t)(nt * 16 + l16) * D_IN + k0);
      acc[nt] = __builtin_amdgcn_mfma_f32_16x16x32_bf16(afrag, bfrag, acc[nt], 0, 0, 0);
    }
  }
#pragma unroll
  for (int r = 0; r < 4; r++) {
    int row = rowbase + quad * 4 + r;
    float sc = dinv[row];
#pragma unroll
    for (int nt = 0; nt < 4; nt++)
      xw1s[(size_t)row * D_HID + nt * 16 + l16] = acc[nt][r] * sc;
  }
}

// ---------- agg1 + gemm2 fused ----------
// h = relu(dd*(Σ_nbr xw1s[s] + xw1s[i]) + b1)  [xw1s pre-scaled by dinv]
// xw2s[i,c] = dd * Σ_k h[k]*W2[k,c]
__global__ __launch_bounds__(256) void k_agg1(const float* __restrict__ xw1s,
    const int* __restrict__ rowptr, const int* __restrict__ csr_src,
    const float* __restrict__ dinv, const float* __restrict__ b1,
    const float* __restrict__ w2, float* __restrict__ xw2s) {
  __shared__ float w2s[D_HID * N_CLS];
  __shared__ float hbuf[4][D_HID];
  for (int i = threadIdx.x; i < D_HID * N_CLS; i += 256) w2s[i] = w2[i];
  __syncthreads();
  int wave = threadIdx.x >> 6;
  int lane = threadIdx.x & 63;
  int node = blockIdx.x * 4 + wave;
  float dd = dinv[node];
  int beg = rowptr[node], end = rowptr[node + 1];
  float a0 = 0.f, a1 = 0.f, a2 = 0.f, a3 = 0.f;
  int e = beg;
  for (; e + 4 <= end; e += 4) {
    int s0 = csr_src[e], s1 = csr_src[e + 1], s2 = csr_src[e + 2], s3 = csr_src[e + 3];
    a0 += xw1s[(size_t)s0 * D_HID + lane];
    a1 += xw1s[(size_t)s1 * D_HID + lane];
    a2 += xw1s[(size_t)s2 * D_HID + lane];
    a3 += xw1s[(size_t)s3 * D_HID + lane];
  }
  for (; e < end; e++) a0 += xw1s[(size_t)csr_src[e] * D_HID + lane];
  float sum = (a0 + a1) + (a2 + a3);
  sum += xw1s[(size_t)node * D_HID + lane];  // self-loop (pre-scaled)
  float v = dd * sum + b1[lane];
  hbuf[wave][lane] = v > 0.f ? v : 0.f;
  __syncthreads();
  // fused layer-2 linear: lanes split k-range in halves, combine via shfl
  int half = lane >> 5, c = lane & 31;
  float p = 0.f;
#pragma unroll
  for (int kk = 0; kk < 32; kk++) {
    int k = half * 32 + kk;
    p += hbuf[wave][k] * w2s[k * N_CLS + c];
  }
  p += __shfl_down(p, 32);
  if (lane < 32) xw2s[(size_t)node * N_CLS + c] = p * dd;
}

// ---------- agg2 + log_softmax ----------
// logit = dd*(Σ_nbr xw2s[s,c] + xw2s[i,c]) + b2[c]
__global__ __launch_bounds__(256) void k_agg2(const float* __restrict__ xw2s,
    const int* __restrict__ rowptr, const int* __restrict__ csr_src,
    const float* __restrict__ dinv, const float* __restrict__ b2,
    float* __restrict__ out) {
  int wave = threadIdx.x >> 6;
  int lane = threadIdx.x & 63;
  int node = blockIdx.x * 4 + wave;
  int half = lane >> 5, c = lane & 31;
  float dd = dinv[node];
  int beg = rowptr[node], end = rowptr[node + 1];
  float a0 = 0.f, a1 = 0.f;
  int e = beg + half;
  for (; e + 3 <= end; e += 4) {  // this half handles e, e+2
    int s0 = csr_src[e], s1 = csr_src[e + 2];
    a0 += xw2s[(size_t)s0 * N_CLS + c];
    a1 += xw2s[(size_t)s1 * N_CLS + c];
  }
  for (; e < end; e += 2) a0 += xw2s[(size_t)csr_src[e] * N_CLS + c];
  float acc = a0 + a1;
  acc += __shfl_down(acc, 32);
  if (lane < 32) {
    acc += xw2s[(size_t)node * N_CLS + c];  // self (pre-scaled)
    float logit = dd * acc + b2[c];
    float m = logit;
#pragma unroll
    for (int o = 16; o > 0; o >>= 1) m = fmaxf(m, __shfl_xor(m, o, 32));
    float ex = __expf(logit - m);
    float ssum = ex;
#pragma unroll
    for (int o = 16; o > 0; o >>= 1) ssum += __shfl_xor(ssum, o, 32);
    out[(size_t)node * N_CLS + c] = logit - m - __logf(ssum);
  }
}

extern "C" void kernel_launch(void* const* d_in, const int* in_sizes, int n_in,
                              void* d_out, int out_size, void* d_ws, size_t ws_size,
                              hipStream_t stream) {
  (void)n_in; (void)out_size; (void)ws_size;
  const float* x  = (const float*)d_in[0];
  const int*   ei = (const int*)d_in[1];
  const float* w1 = (const float*)d_in[2];
  const float* b1 = (const float*)d_in[3];
  const float* w2 = (const float*)d_in[4];
  const float* b2 = (const float*)d_in[5];
  float* out = (float*)d_out;
  int e = in_sizes[1] / 2;
  const int* src = ei;
  const int* dst = ei + e;

  char* ws = (char*)d_ws;
  int* cnt            = (int*)(ws + 0x000000);            // 256KB
  int* rowptr         = (int*)(ws + 0x040000);            // 256KB + 4
  int* cursor         = (int*)(ws + 0x0C0000);            // 256KB
  float* dinv         = (float*)(ws + 0x100000);          // 256KB
  int* bsum           = (int*)(ws + 0x140000);            // 1KB
  int* boff           = (int*)(ws + 0x141000);            // 1KB
  int* csr_src        = (int*)(ws + 0x180000);            // 4MB
  unsigned short* w1t = (unsigned short*)(ws + 0x580000); // 128KB
  float* xw1s         = (float*)(ws + 0x600000);          // 16MB
  float* xw2s         = (float*)(ws + 0x1600000);         // 8MB

  int e4 = e / 4;
  hipMemsetAsync(cnt, 0, N_NODES * sizeof(int), stream);
  k_count <<<(e4 + 255) / 256, 256, 0, stream>>>(dst, cnt, e4);
  k_dinv  <<<N_NODES / 256, 256, 0, stream>>>(cnt, dinv);
  k_scan_a<<<N_NODES / 256, 256, 0, stream>>>(cnt, bsum);
  k_scan_b<<<1, 256, 0, stream>>>(bsum, boff);
  k_scan_c<<<N_NODES / 256, 256, 0, stream>>>(cnt, boff, rowptr, cursor);
  k_fill  <<<(e4 + 255) / 256, 256, 0, stream>>>(src, dst, cursor, csr_src, e4);
  k_w1t   <<<(D_IN * D_HID) / 256, 256, 0, stream>>>(w1, w1t);
  k_gemm1 <<<N_NODES / 64, 256, 0, stream>>>(x, w1t, dinv, xw1s);
  k_agg1  <<<N_NODES / 4, 256, 0, stream>>>(xw1s, rowptr, csr_src, dinv, b1, w2, xw2s);
  k_agg2  <<<N_NODES / 4, 256, 0, stream>>>(xw2s, rowptr, csr_src, dinv, b2, out);
}

// Round 4
// 602.562 us; speedup vs baseline: 1.1984x; 1.0146x over previous
//
#include <hip/hip_runtime.h>
#include <hip/hip_bf16.h>

#define N_NODES 65536
#define D_IN 1024
#define D_HID 64
#define N_CLS 32

typedef short short8 __attribute__((ext_vector_type(8)));
typedef float floatx4 __attribute__((ext_vector_type(4)));

// ---------- helpers ----------
__device__ __forceinline__ unsigned short f2bf(float f) {
  union { float f; unsigned u; } cv; cv.f = f;
  unsigned r = (cv.u + 0x7FFFu + ((cv.u >> 16) & 1u)) >> 16;
  return (unsigned short)r;
}
__device__ __forceinline__ unsigned pack_bf2(float x, float y) {
  return (unsigned)f2bf(x) | ((unsigned)f2bf(y) << 16);
}
__device__ __forceinline__ float2 bf2f2(unsigned v) {
  union { unsigned u; float f; } a, b;
  a.u = v << 16;
  b.u = v & 0xFFFF0000u;
  return make_float2(a.f, b.f);  // (elem 2l, elem 2l+1)
}

// ---------- degree count (4 edges/thread) ----------
__global__ void k_count(const int* __restrict__ dst, int* __restrict__ cnt, int e4) {
  int i = blockIdx.x * blockDim.x + threadIdx.x;
  if (i < e4) {
    int4 d = ((const int4*)dst)[i];
    atomicAdd(&cnt[d.x], 1);
    atomicAdd(&cnt[d.y], 1);
    atomicAdd(&cnt[d.z], 1);
    atomicAdd(&cnt[d.w], 1);
  }
}

// ---------- scan phase A: per-block sums ----------
__global__ void k_scan_a(const int* __restrict__ cnt, int* __restrict__ bsum) {
  __shared__ int s[256];
  int t = threadIdx.x;
  s[t] = cnt[blockIdx.x * 256 + t];
  __syncthreads();
  for (int off = 128; off > 0; off >>= 1) {
    if (t < off) s[t] += s[t + off];
    __syncthreads();
  }
  if (t == 0) bsum[blockIdx.x] = s[0];
}

// ---------- scan phase B (block 256) + W1 transpose->bf16 (blocks 0..255) ----------
__global__ void k_scanb_w1t(int* __restrict__ bsum, int* __restrict__ boff,
                            const float* __restrict__ w1, unsigned short* __restrict__ w1t) {
  if (blockIdx.x < 256) {
    int i = blockIdx.x * 256 + threadIdx.x;  // i < 65536 = D_IN*D_HID
    int k = i / D_HID, n = i % D_HID;
    w1t[n * D_IN + k] = f2bf(w1[i]);
    return;
  }
  __shared__ int s[256];
  int t = threadIdx.x;
  int v = bsum[t];
  s[t] = v;
  __syncthreads();
  for (int off = 1; off < 256; off <<= 1) {
    int x = (t >= off) ? s[t - off] : 0;
    __syncthreads();
    s[t] += x;
    __syncthreads();
  }
  boff[t] = s[t] - v;  // exclusive
}

// ---------- scan phase C: rowptr/cursor + dinv ----------
__global__ void k_scan_c(const int* __restrict__ cnt, const int* __restrict__ boff,
                         int* __restrict__ rowptr, int* __restrict__ cursor,
                         float* __restrict__ dinv) {
  __shared__ int s[256];
  int t = threadIdx.x;
  int i = blockIdx.x * 256 + t;
  int v = cnt[i];
  s[t] = v;
  __syncthreads();
  for (int off = 1; off < 256; off <<= 1) {
    int x = (t >= off) ? s[t - off] : 0;
    __syncthreads();
    s[t] += x;
    __syncthreads();
  }
  int excl = s[t] - v + boff[blockIdx.x];
  rowptr[i] = excl;
  cursor[i] = excl;
  dinv[i] = rsqrtf((float)(v + 1));
  if (i == N_NODES - 1) rowptr[N_NODES] = excl + v;
}

// ---------- CSR fill ----------
__global__ void k_fill(const int* __restrict__ src, const int* __restrict__ dst,
                       int* __restrict__ cursor, int* __restrict__ csr_src, int e4) {
  int i = blockIdx.x * blockDim.x + threadIdx.x;
  if (i < e4) {
    int4 d = ((const int4*)dst)[i];
    int4 s = ((const int4*)src)[i];
    csr_src[atomicAdd(&cursor[d.x], 1)] = s.x;
    csr_src[atomicAdd(&cursor[d.y], 1)] = s.y;
    csr_src[atomicAdd(&cursor[d.z], 1)] = s.z;
    csr_src[atomicAdd(&cursor[d.w], 1)] = s.w;
  }
}

// ---------- GEMM1: xw1s[N,64](bf16) = dinv[i]*(x @ W1); 32 rows/wave ----------
__global__ __launch_bounds__(256) void k_gemm1(const float* __restrict__ x,
    const unsigned short* __restrict__ w1t, const float* __restrict__ dinv,
    unsigned short* __restrict__ xw1s) {
  int wave = threadIdx.x >> 6;
  int lane = threadIdx.x & 63;
  int quad = lane >> 4;
  int l16 = lane & 15;
  int rowbase = blockIdx.x * 128 + wave * 32;
  const float* xr0 = x + (size_t)(rowbase + l16) * D_IN + quad * 8;
  const float* xr1 = xr0 + (size_t)16 * D_IN;
  floatx4 acc[2][4];
#pragma unroll
  for (int mt = 0; mt < 2; mt++)
#pragma unroll
    for (int nt = 0; nt < 4; nt++) acc[mt][nt] = (floatx4){0.f, 0.f, 0.f, 0.f};
  const unsigned short* bbase = w1t + quad * 8;
#pragma unroll 2
  for (int k0 = 0; k0 < D_IN; k0 += 32) {
    float4 a0 = *(const float4*)(xr0 + k0);
    float4 a1 = *(const float4*)(xr0 + k0 + 4);
    float4 a2 = *(const float4*)(xr1 + k0);
    float4 a3 = *(const float4*)(xr1 + k0 + 4);
    float av0[8] = {a0.x, a0.y, a0.z, a0.w, a1.x, a1.y, a1.z, a1.w};
    float av1[8] = {a2.x, a2.y, a2.z, a2.w, a3.x, a3.y, a3.z, a3.w};
    short8 af0, af1;
#pragma unroll
    for (int j = 0; j < 8; j++) { af0[j] = (short)f2bf(av0[j]); af1[j] = (short)f2bf(av1[j]); }
#pragma unroll
    for (int nt = 0; nt < 4; nt++) {
      short8 bf = *(const short8*)(bbase + (size_t)(nt * 16 + l16) * D_IN + k0);
      acc[0][nt] = __builtin_amdgcn_mfma_f32_16x16x32_bf16(af0, bf, acc[0][nt], 0, 0, 0);
      acc[1][nt] = __builtin_amdgcn_mfma_f32_16x16x32_bf16(af1, bf, acc[1][nt], 0, 0, 0);
    }
  }
#pragma unroll
  for (int mt = 0; mt < 2; mt++)
#pragma unroll
    for (int r = 0; r < 4; r++) {
      int row = rowbase + mt * 16 + quad * 4 + r;
      float sc = dinv[row];
#pragma unroll
      for (int nt = 0; nt < 4; nt++)
        xw1s[(size_t)row * D_HID + nt * 16 + l16] = f2bf(acc[mt][nt][r] * sc);
    }
}

// ---------- agg1 + gemm2 fused; bf16 gathers, half-wave per edge ----------
__global__ __launch_bounds__(256) void k_agg1(const unsigned* __restrict__ xw1s2,
    const int* __restrict__ rowptr, const int* __restrict__ csr_src,
    const float* __restrict__ dinv, const float* __restrict__ b1,
    const float* __restrict__ w2, unsigned short* __restrict__ xw2s) {
  __shared__ float w2s[D_HID * N_CLS];
  __shared__ float2 hbuf[4][32];
  for (int i = threadIdx.x; i < D_HID * N_CLS; i += 256) w2s[i] = w2[i];
  __syncthreads();
  int wave = threadIdx.x >> 6;
  int lane = threadIdx.x & 63;
  int h = lane >> 5, l = lane & 31;
  int node = blockIdx.x * 4 + wave;
  float dd = dinv[node];
  int beg = rowptr[node], end = rowptr[node + 1];
  float2 c0 = {0.f, 0.f}, c1 = {0.f, 0.f}, c2 = {0.f, 0.f}, c3 = {0.f, 0.f};
  int e = beg + h;
  for (; e + 6 < end; e += 8) {
    int s0 = csr_src[e], s1 = csr_src[e + 2], s2 = csr_src[e + 4], s3 = csr_src[e + 6];
    float2 v0 = bf2f2(xw1s2[(size_t)s0 * 32 + l]);
    float2 v1 = bf2f2(xw1s2[(size_t)s1 * 32 + l]);
    float2 v2 = bf2f2(xw1s2[(size_t)s2 * 32 + l]);
    float2 v3 = bf2f2(xw1s2[(size_t)s3 * 32 + l]);
    c0.x += v0.x; c0.y += v0.y; c1.x += v1.x; c1.y += v1.y;
    c2.x += v2.x; c2.y += v2.y; c3.x += v3.x; c3.y += v3.y;
  }
  for (; e < end; e += 2) {
    float2 v = bf2f2(xw1s2[(size_t)csr_src[e] * 32 + l]);
    c0.x += v.x; c0.y += v.y;
  }
  float sx = (c0.x + c1.x) + (c2.x + c3.x);
  float sy = (c0.y + c1.y) + (c2.y + c3.y);
  sx += __shfl_down(sx, 32);
  sy += __shfl_down(sy, 32);
  if (lane < 32) {
    float2 self = bf2f2(xw1s2[(size_t)node * 32 + l]);
    float2 bb = ((const float2*)b1)[l];
    float vx = dd * (sx + self.x) + bb.x;
    float vy = dd * (sy + self.y) + bb.y;
    hbuf[wave][l] = make_float2(vx > 0.f ? vx : 0.f, vy > 0.f ? vy : 0.f);
  }
  __syncthreads();
  // fused layer-2 linear: halves split k, combine via shfl
  const float* hb = (const float*)hbuf[wave];
  int c = lane & 31;
  float p = 0.f;
#pragma unroll
  for (int kk = 0; kk < 32; kk++) {
    int k = h * 32 + kk;
    p += hb[k] * w2s[k * N_CLS + c];
  }
  p += __shfl_down(p, 32);
  if (lane < 32) xw2s[(size_t)node * N_CLS + c] = f2bf(p * dd);
}

// ---------- agg2 + log_softmax; bf16 gathers, quarter-wave per edge ----------
__global__ __launch_bounds__(256) void k_agg2(const unsigned* __restrict__ xw2s2,
    const int* __restrict__ rowptr, const int* __restrict__ csr_src,
    const float* __restrict__ dinv, const float* __restrict__ b2,
    float* __restrict__ out) {
  int wave = threadIdx.x >> 6;
  int lane = threadIdx.x & 63;
  int q = lane >> 4, l = lane & 15;
  int node = blockIdx.x * 4 + wave;
  float dd = dinv[node];
  int beg = rowptr[node], end = rowptr[node + 1];
  float2 c0 = {0.f, 0.f}, c1 = {0.f, 0.f};
  int e = beg + q;
  for (; e + 4 < end; e += 8) {
    int s0 = csr_src[e], s1 = csr_src[e + 4];
    float2 v0 = bf2f2(xw2s2[(size_t)s0 * 16 + l]);
    float2 v1 = bf2f2(xw2s2[(size_t)s1 * 16 + l]);
    c0.x += v0.x; c0.y += v0.y; c1.x += v1.x; c1.y += v1.y;
  }
  for (; e < end; e += 4) {
    float2 v = bf2f2(xw2s2[(size_t)csr_src[e] * 16 + l]);
    c0.x += v.x; c0.y += v.y;
  }
  float sx = c0.x + c1.x;
  float sy = c0.y + c1.y;
  sx += __shfl_down(sx, 32); sy += __shfl_down(sy, 32);
  sx += __shfl_down(sx, 16); sy += __shfl_down(sy, 16);
  if (lane < 16) {
    float2 self = bf2f2(xw2s2[(size_t)node * 16 + l]);
    float2 bb = ((const float2*)b2)[l];
    float lx = dd * (sx + self.x) + bb.x;
    float ly = dd * (sy + self.y) + bb.y;
    float m = fmaxf(lx, ly);
#pragma unroll
    for (int o = 8; o > 0; o >>= 1) m = fmaxf(m, __shfl_xor(m, o));
    float s2 = __expf(lx - m) + __expf(ly - m);
#pragma unroll
    for (int o = 8; o > 0; o >>= 1) s2 += __shfl_xor(s2, o);
    float lse = m + __logf(s2);
    ((float2*)out)[(size_t)node * 16 + l] = make_float2(lx - lse, ly - lse);
  }
}

extern "C" void kernel_launch(void* const* d_in, const int* in_sizes, int n_in,
                              void* d_out, int out_size, void* d_ws, size_t ws_size,
                              hipStream_t stream) {
  (void)n_in; (void)out_size; (void)ws_size;
  const float* x  = (const float*)d_in[0];
  const int*   ei = (const int*)d_in[1];
  const float* w1 = (const float*)d_in[2];
  const float* b1 = (const float*)d_in[3];
  const float* w2 = (const float*)d_in[4];
  const float* b2 = (const float*)d_in[5];
  float* out = (float*)d_out;
  int e = in_sizes[1] / 2;
  const int* src = ei;
  const int* dst = ei + e;

  char* ws = (char*)d_ws;
  int* cnt            = (int*)(ws + 0x000000);            // 256KB
  int* rowptr         = (int*)(ws + 0x040000);            // 256KB + 4
  int* cursor         = (int*)(ws + 0x0C0000);            // 256KB
  float* dinv         = (float*)(ws + 0x100000);          // 256KB
  int* bsum           = (int*)(ws + 0x140000);            // 1KB
  int* boff           = (int*)(ws + 0x141000);            // 1KB
  int* csr_src        = (int*)(ws + 0x180000);            // 4MB
  unsigned short* w1t = (unsigned short*)(ws + 0x580000); // 128KB
  unsigned short* xw1s= (unsigned short*)(ws + 0x600000); // 8MB (bf16)
  unsigned short* xw2s= (unsigned short*)(ws + 0xE00000); // 4MB (bf16)

  int e4 = e / 4;
  hipMemsetAsync(cnt, 0, N_NODES * sizeof(int), stream);
  k_count   <<<(e4 + 255) / 256, 256, 0, stream>>>(dst, cnt, e4);
  k_scan_a  <<<N_NODES / 256, 256, 0, stream>>>(cnt, bsum);
  k_scanb_w1t<<<257, 256, 0, stream>>>(bsum, boff, w1, w1t);
  k_scan_c  <<<N_NODES / 256, 256, 0, stream>>>(cnt, boff, rowptr, cursor, dinv);
  k_fill    <<<(e4 + 255) / 256, 256, 0, stream>>>(src, dst, cursor, csr_src, e4);
  k_gemm1   <<<N_NODES / 128, 256, 0, stream>>>(x, w1t, dinv, xw1s);
  k_agg1    <<<N_NODES / 4, 256, 0, stream>>>((const unsigned*)xw1s, rowptr, csr_src,
                                              dinv, b1, w2, xw2s);
  k_agg2    <<<N_NODES / 4, 256, 0, stream>>>((const unsigned*)xw2s, rowptr, csr_src,
                                              dinv, b2, out);
}

// Round 5
// 588.563 us; speedup vs baseline: 1.2269x; 1.0238x over previous
//
#include <hip/hip_runtime.h>
#include <hip/hip_bf16.h>

#define N_NODES 65536
#define D_IN 1024
#define D_HID 64
#define N_CLS 32

typedef short short8 __attribute__((ext_vector_type(8)));
typedef float floatx4 __attribute__((ext_vector_type(4)));

// ---------- helpers ----------
__device__ __forceinline__ unsigned short f2bf(float f) {
  union { float f; unsigned u; } cv; cv.f = f;
  unsigned r = (cv.u + 0x7FFFu + ((cv.u >> 16) & 1u)) >> 16;
  return (unsigned short)r;
}
__device__ __forceinline__ float2 bf2f2(unsigned v) {
  union { unsigned u; float f; } a, b;
  a.u = v << 16;
  b.u = v & 0xFFFF0000u;
  return make_float2(a.f, b.f);  // (elem 2l, elem 2l+1)
}

// ---------- count (blocks 0..1023) + W1 transpose->bf16 (blocks 1024..1279) ----------
__global__ void k_count_w1t(const int* __restrict__ dst, int* __restrict__ cnt,
                            const float* __restrict__ w1, unsigned short* __restrict__ w1t,
                            int e4) {
  int b = blockIdx.x;
  if (b >= 1024) {
    int i = (b - 1024) * 256 + threadIdx.x;  // [0, 65536)
    int k = i / D_HID, n = i % D_HID;
    w1t[n * D_IN + k] = f2bf(w1[i]);
    return;
  }
  int i = b * 256 + threadIdx.x;
  if (i < e4) {
    int4 d = ((const int4*)dst)[i];
    atomicAdd(&cnt[d.x], 1);
    atomicAdd(&cnt[d.y], 1);
    atomicAdd(&cnt[d.z], 1);
    atomicAdd(&cnt[d.w], 1);
  }
}

// ---------- scan phase A: per-block sums ----------
__global__ void k_scan_a(const int* __restrict__ cnt, int* __restrict__ bsum) {
  __shared__ int s[256];
  int t = threadIdx.x;
  s[t] = cnt[blockIdx.x * 256 + t];
  __syncthreads();
  for (int off = 128; off > 0; off >>= 1) {
    if (t < off) s[t] += s[t + off];
    __syncthreads();
  }
  if (t == 0) bsum[blockIdx.x] = s[0];
}

// ---------- scan phase C: inline block-offset reduce + rowptr/cursor/dinv ----------
__global__ void k_scan_c(const int* __restrict__ cnt, const int* __restrict__ bsum,
                         int* __restrict__ rowptr, int* __restrict__ cursor,
                         float* __restrict__ dinv) {
  __shared__ int s[256];
  int t = threadIdx.x;
  // block offset = sum_{j < blockIdx.x} bsum[j]
  s[t] = (t < blockIdx.x) ? bsum[t] : 0;
  __syncthreads();
  for (int off = 128; off > 0; off >>= 1) {
    if (t < off) s[t] += s[t + off];
    __syncthreads();
  }
  int blockoff = s[0];
  __syncthreads();
  int i = blockIdx.x * 256 + t;
  int v = cnt[i];
  s[t] = v;
  __syncthreads();
  for (int off = 1; off < 256; off <<= 1) {
    int x = (t >= off) ? s[t - off] : 0;
    __syncthreads();
    s[t] += x;
    __syncthreads();
  }
  int excl = s[t] - v + blockoff;
  rowptr[i] = excl;
  cursor[i] = excl;
  dinv[i] = rsqrtf((float)(v + 1));
  if (i == N_NODES - 1) rowptr[N_NODES] = excl + v;
}

// ---------- GEMM1 (blocks 0..511) + CSR fill (blocks 512..1535) ----------
__global__ __launch_bounds__(256) void k_fill_gemm1(
    const int* __restrict__ src, const int* __restrict__ dst,
    int* __restrict__ cursor, int* __restrict__ csr_src, int e4,
    const float* __restrict__ x, const unsigned short* __restrict__ w1t,
    const float* __restrict__ dinv, unsigned short* __restrict__ xw1s) {
  if (blockIdx.x >= 512) {
    int i = (blockIdx.x - 512) * 256 + threadIdx.x;
    if (i < e4) {
      int4 d = ((const int4*)dst)[i];
      int4 s = ((const int4*)src)[i];
      csr_src[atomicAdd(&cursor[d.x], 1)] = s.x;
      csr_src[atomicAdd(&cursor[d.y], 1)] = s.y;
      csr_src[atomicAdd(&cursor[d.z], 1)] = s.z;
      csr_src[atomicAdd(&cursor[d.w], 1)] = s.w;
    }
    return;
  }
  int wave = threadIdx.x >> 6;
  int lane = threadIdx.x & 63;
  int quad = lane >> 4;
  int l16 = lane & 15;
  int rowbase = blockIdx.x * 128 + wave * 32;
  const float* xr0 = x + (size_t)(rowbase + l16) * D_IN + quad * 8;
  const float* xr1 = xr0 + (size_t)16 * D_IN;
  floatx4 acc[2][4];
#pragma unroll
  for (int mt = 0; mt < 2; mt++)
#pragma unroll
    for (int nt = 0; nt < 4; nt++) acc[mt][nt] = (floatx4){0.f, 0.f, 0.f, 0.f};
  const unsigned short* bbase = w1t + quad * 8;
#pragma unroll 2
  for (int k0 = 0; k0 < D_IN; k0 += 32) {
    float4 a0 = *(const float4*)(xr0 + k0);
    float4 a1 = *(const float4*)(xr0 + k0 + 4);
    float4 a2 = *(const float4*)(xr1 + k0);
    float4 a3 = *(const float4*)(xr1 + k0 + 4);
    float av0[8] = {a0.x, a0.y, a0.z, a0.w, a1.x, a1.y, a1.z, a1.w};
    float av1[8] = {a2.x, a2.y, a2.z, a2.w, a3.x, a3.y, a3.z, a3.w};
    short8 af0, af1;
#pragma unroll
    for (int j = 0; j < 8; j++) { af0[j] = (short)f2bf(av0[j]); af1[j] = (short)f2bf(av1[j]); }
#pragma unroll
    for (int nt = 0; nt < 4; nt++) {
      short8 bf = *(const short8*)(bbase + (size_t)(nt * 16 + l16) * D_IN + k0);
      acc[0][nt] = __builtin_amdgcn_mfma_f32_16x16x32_bf16(af0, bf, acc[0][nt], 0, 0, 0);
      acc[1][nt] = __builtin_amdgcn_mfma_f32_16x16x32_bf16(af1, bf, acc[1][nt], 0, 0, 0);
    }
  }
#pragma unroll
  for (int mt = 0; mt < 2; mt++)
#pragma unroll
    for (int r = 0; r < 4; r++) {
      int row = rowbase + mt * 16 + quad * 4 + r;
      float sc = dinv[row];
#pragma unroll
      for (int nt = 0; nt < 4; nt++)
        xw1s[(size_t)row * D_HID + nt * 16 + l16] = f2bf(acc[mt][nt][r] * sc);
    }
}

// ---------- agg1 + gemm2 fused; 8 gather streams per half-wave ----------
__global__ __launch_bounds__(256) void k_agg1(const unsigned* __restrict__ xw1s2,
    const int* __restrict__ rowptr, const int* __restrict__ csr_src,
    const float* __restrict__ dinv, const float* __restrict__ b1,
    const float* __restrict__ w2, unsigned short* __restrict__ xw2s) {
  __shared__ float w2s[D_HID * N_CLS];
  __shared__ float2 hbuf[4][32];
  for (int i = threadIdx.x; i < D_HID * N_CLS; i += 256) w2s[i] = w2[i];
  __syncthreads();
  int wave = threadIdx.x >> 6;
  int lane = threadIdx.x & 63;
  int h = lane >> 5, l = lane & 31;
  int node = blockIdx.x * 4 + wave;
  float dd = dinv[node];
  int beg = rowptr[node], end = rowptr[node + 1];
  float cx[8], cy[8];
#pragma unroll
  for (int j = 0; j < 8; j++) { cx[j] = 0.f; cy[j] = 0.f; }
  int e = beg + h;
  for (; e + 14 < end; e += 16) {
    int idx[8];
#pragma unroll
    for (int j = 0; j < 8; j++) idx[j] = csr_src[e + 2 * j];
#pragma unroll
    for (int j = 0; j < 8; j++) {
      float2 v = bf2f2(xw1s2[(size_t)idx[j] * 32 + l]);
      cx[j] += v.x; cy[j] += v.y;
    }
  }
  for (; e < end; e += 2) {
    float2 v = bf2f2(xw1s2[(size_t)csr_src[e] * 32 + l]);
    cx[0] += v.x; cy[0] += v.y;
  }
  float sx = ((cx[0] + cx[1]) + (cx[2] + cx[3])) + ((cx[4] + cx[5]) + (cx[6] + cx[7]));
  float sy = ((cy[0] + cy[1]) + (cy[2] + cy[3])) + ((cy[4] + cy[5]) + (cy[6] + cy[7]));
  sx += __shfl_down(sx, 32);
  sy += __shfl_down(sy, 32);
  if (lane < 32) {
    float2 self = bf2f2(xw1s2[(size_t)node * 32 + l]);
    float2 bb = ((const float2*)b1)[l];
    float vx = dd * (sx + self.x) + bb.x;
    float vy = dd * (sy + self.y) + bb.y;
    hbuf[wave][l] = make_float2(vx > 0.f ? vx : 0.f, vy > 0.f ? vy : 0.f);
  }
  __syncthreads();
  const float* hb = (const float*)hbuf[wave];
  int c = lane & 31;
  float p = 0.f;
#pragma unroll
  for (int kk = 0; kk < 32; kk++) {
    int k = h * 32 + kk;
    p += hb[k] * w2s[k * N_CLS + c];
  }
  p += __shfl_down(p, 32);
  if (lane < 32) xw2s[(size_t)node * N_CLS + c] = f2bf(p * dd);
}

// ---------- agg2 + log_softmax; 4 gather streams per quarter-wave ----------
__global__ __launch_bounds__(256) void k_agg2(const unsigned* __restrict__ xw2s2,
    const int* __restrict__ rowptr, const int* __restrict__ csr_src,
    const float* __restrict__ dinv, const float* __restrict__ b2,
    float* __restrict__ out) {
  int wave = threadIdx.x >> 6;
  int lane = threadIdx.x & 63;
  int q = lane >> 4, l = lane & 15;
  int node = blockIdx.x * 4 + wave;
  float dd = dinv[node];
  int beg = rowptr[node], end = rowptr[node + 1];
  float cx[4], cy[4];
#pragma unroll
  for (int j = 0; j < 4; j++) { cx[j] = 0.f; cy[j] = 0.f; }
  int e = beg + q;
  for (; e + 12 < end; e += 16) {
    int idx[4];
#pragma unroll
    for (int j = 0; j < 4; j++) idx[j] = csr_src[e + 4 * j];
#pragma unroll
    for (int j = 0; j < 4; j++) {
      float2 v = bf2f2(xw2s2[(size_t)idx[j] * 16 + l]);
      cx[j] += v.x; cy[j] += v.y;
    }
  }
  for (; e < end; e += 4) {
    float2 v = bf2f2(xw2s2[(size_t)csr_src[e] * 16 + l]);
    cx[0] += v.x; cy[0] += v.y;
  }
  float sx = (cx[0] + cx[1]) + (cx[2] + cx[3]);
  float sy = (cy[0] + cy[1]) + (cy[2] + cy[3]);
  sx += __shfl_down(sx, 32); sy += __shfl_down(sy, 32);
  sx += __shfl_down(sx, 16); sy += __shfl_down(sy, 16);
  if (lane < 16) {
    float2 self = bf2f2(xw2s2[(size_t)node * 16 + l]);
    float2 bb = ((const float2*)b2)[l];
    float lx = dd * (sx + self.x) + bb.x;
    float ly = dd * (sy + self.y) + bb.y;
    float m = fmaxf(lx, ly);
#pragma unroll
    for (int o = 8; o > 0; o >>= 1) m = fmaxf(m, __shfl_xor(m, o));
    float s2 = __expf(lx - m) + __expf(ly - m);
#pragma unroll
    for (int o = 8; o > 0; o >>= 1) s2 += __shfl_xor(s2, o);
    float lse = m + __logf(s2);
    ((float2*)out)[(size_t)node * 16 + l] = make_float2(lx - lse, ly - lse);
  }
}

extern "C" void kernel_launch(void* const* d_in, const int* in_sizes, int n_in,
                              void* d_out, int out_size, void* d_ws, size_t ws_size,
                              hipStream_t stream) {
  (void)n_in; (void)out_size; (void)ws_size;
  const float* x  = (const float*)d_in[0];
  const int*   ei = (const int*)d_in[1];
  const float* w1 = (const float*)d_in[2];
  const float* b1 = (const float*)d_in[3];
  const float* w2 = (const float*)d_in[4];
  const float* b2 = (const float*)d_in[5];
  float* out = (float*)d_out;
  int e = in_sizes[1] / 2;
  const int* src = ei;
  const int* dst = ei + e;

  char* ws = (char*)d_ws;
  int* cnt            = (int*)(ws + 0x000000);            // 256KB
  int* rowptr         = (int*)(ws + 0x040000);            // 256KB + 4
  int* cursor         = (int*)(ws + 0x0C0000);            // 256KB
  float* dinv         = (float*)(ws + 0x100000);          // 256KB
  int* bsum           = (int*)(ws + 0x140000);            // 1KB
  int* csr_src        = (int*)(ws + 0x180000);            // 4MB
  unsigned short* w1t = (unsigned short*)(ws + 0x580000); // 128KB
  unsigned short* xw1s= (unsigned short*)(ws + 0x600000); // 8MB (bf16)
  unsigned short* xw2s= (unsigned short*)(ws + 0xE00000); // 4MB (bf16)

  int e4 = e / 4;
  hipMemsetAsync(cnt, 0, N_NODES * sizeof(int), stream);
  k_count_w1t<<<1280, 256, 0, stream>>>(dst, cnt, w1, w1t, e4);
  k_scan_a   <<<N_NODES / 256, 256, 0, stream>>>(cnt, bsum);
  k_scan_c   <<<N_NODES / 256, 256, 0, stream>>>(cnt, bsum, rowptr, cursor, dinv);
  k_fill_gemm1<<<1536, 256, 0, stream>>>(src, dst, cursor, csr_src, e4,
                                         x, w1t, dinv, xw1s);
  k_agg1     <<<N_NODES / 4, 256, 0, stream>>>((const unsigned*)xw1s, rowptr, csr_src,
                                               dinv, b1, w2, xw2s);
  k_agg2     <<<N_NODES / 4, 256, 0, stream>>>((const unsigned*)xw2s, rowptr, csr_src,
                                               dinv, b2, out);
}

// Round 6
// 563.434 us; speedup vs baseline: 1.2817x; 1.0446x over previous
//
#include <hip/hip_runtime.h>
#include <hip/hip_bf16.h>

#define N_NODES 65536
#define D_IN 1024
#define D_HID 64
#define N_CLS 32

typedef short short8 __attribute__((ext_vector_type(8)));
typedef float floatx4 __attribute__((ext_vector_type(4)));

// ---------- helpers ----------
__device__ __forceinline__ unsigned short f2bf(float f) {
  union { float f; unsigned u; } cv; cv.f = f;
  unsigned r = (cv.u + 0x7FFFu + ((cv.u >> 16) & 1u)) >> 16;
  return (unsigned short)r;
}
__device__ __forceinline__ float2 bf2f2(unsigned v) {
  union { unsigned u; float f; } a, b;
  a.u = v << 16;
  b.u = v & 0xFFFF0000u;
  return make_float2(a.f, b.f);  // (elem 2l, elem 2l+1)
}

// ---------- count (blocks 0..1023) + W1 transpose->bf16 (blocks 1024..1279) ----------
__global__ void k_count_w1t(const int* __restrict__ dst, int* __restrict__ cnt,
                            const float* __restrict__ w1, unsigned short* __restrict__ w1t,
                            int e4) {
  int b = blockIdx.x;
  if (b >= 1024) {
    int i = (b - 1024) * 256 + threadIdx.x;  // [0, 65536)
    int k = i / D_HID, n = i % D_HID;
    w1t[n * D_IN + k] = f2bf(w1[i]);
    return;
  }
  int i = b * 256 + threadIdx.x;
  if (i < e4) {
    int4 d = ((const int4*)dst)[i];
    atomicAdd(&cnt[d.x], 1);
    atomicAdd(&cnt[d.y], 1);
    atomicAdd(&cnt[d.z], 1);
    atomicAdd(&cnt[d.w], 1);
  }
}

// ---------- scan phase A: per-block sums ----------
__global__ void k_scan_a(const int* __restrict__ cnt, int* __restrict__ bsum) {
  __shared__ int s[256];
  int t = threadIdx.x;
  s[t] = cnt[blockIdx.x * 256 + t];
  __syncthreads();
  for (int off = 128; off > 0; off >>= 1) {
    if (t < off) s[t] += s[t + off];
    __syncthreads();
  }
  if (t == 0) bsum[blockIdx.x] = s[0];
}

// ---------- scan phase C: inline block-offset reduce + rowptr/cursor/dinv ----------
__global__ void k_scan_c(const int* __restrict__ cnt, const int* __restrict__ bsum,
                         int* __restrict__ rowptr, int* __restrict__ cursor,
                         float* __restrict__ dinv) {
  __shared__ int s[256];
  int t = threadIdx.x;
  s[t] = (t < blockIdx.x) ? bsum[t] : 0;
  __syncthreads();
  for (int off = 128; off > 0; off >>= 1) {
    if (t < off) s[t] += s[t + off];
    __syncthreads();
  }
  int blockoff = s[0];
  __syncthreads();
  int i = blockIdx.x * 256 + t;
  int v = cnt[i];
  s[t] = v;
  __syncthreads();
  for (int off = 1; off < 256; off <<= 1) {
    int x = (t >= off) ? s[t - off] : 0;
    __syncthreads();
    s[t] += x;
    __syncthreads();
  }
  int excl = s[t] - v + blockoff;
  rowptr[i] = excl;
  cursor[i] = excl;
  dinv[i] = rsqrtf((float)(v + 1));
  if (i == N_NODES - 1) rowptr[N_NODES] = excl + v;
}

// ---------- GEMM1 (blocks 0..1023, 16 rows/wave) + CSR fill (blocks 1024..2047) ----------
__global__ __launch_bounds__(256) void k_fill_gemm1(
    const int* __restrict__ src, const int* __restrict__ dst,
    int* __restrict__ cursor, int* __restrict__ csr_src, int e4,
    const float* __restrict__ x, const unsigned short* __restrict__ w1t,
    const float* __restrict__ dinv, unsigned short* __restrict__ xw1s) {
  if (blockIdx.x >= 1024) {
    int i = (blockIdx.x - 1024) * 256 + threadIdx.x;
    if (i < e4) {
      int4 d = ((const int4*)dst)[i];
      int4 s = ((const int4*)src)[i];
      csr_src[atomicAdd(&cursor[d.x], 1)] = s.x;
      csr_src[atomicAdd(&cursor[d.y], 1)] = s.y;
      csr_src[atomicAdd(&cursor[d.z], 1)] = s.z;
      csr_src[atomicAdd(&cursor[d.w], 1)] = s.w;
    }
    return;
  }
  int wave = threadIdx.x >> 6;
  int lane = threadIdx.x & 63;
  int quad = lane >> 4;
  int l16 = lane & 15;
  int rowbase = blockIdx.x * 64 + wave * 16;
  const float* xrow = x + (size_t)(rowbase + l16) * D_IN + quad * 8;
  const unsigned short* bbase = w1t + quad * 8;
  floatx4 acc[4];
#pragma unroll
  for (int nt = 0; nt < 4; nt++) acc[nt] = (floatx4){0.f, 0.f, 0.f, 0.f};
  // prefetch first 64-k chunk (4 independent HBM loads in flight)
  float4 p0 = *(const float4*)(xrow + 0);
  float4 p1 = *(const float4*)(xrow + 4);
  float4 p2 = *(const float4*)(xrow + 32);
  float4 p3 = *(const float4*)(xrow + 36);
  for (int k0 = 0; k0 < D_IN; k0 += 64) {
    float4 c0 = p0, c1 = p1, c2 = p2, c3 = p3;
    if (k0 + 64 < D_IN) {
      p0 = *(const float4*)(xrow + k0 + 64);
      p1 = *(const float4*)(xrow + k0 + 68);
      p2 = *(const float4*)(xrow + k0 + 96);
      p3 = *(const float4*)(xrow + k0 + 100);
    }
    float av0[8] = {c0.x, c0.y, c0.z, c0.w, c1.x, c1.y, c1.z, c1.w};
    float av1[8] = {c2.x, c2.y, c2.z, c2.w, c3.x, c3.y, c3.z, c3.w};
    short8 af0, af1;
#pragma unroll
    for (int j = 0; j < 8; j++) { af0[j] = (short)f2bf(av0[j]); af1[j] = (short)f2bf(av1[j]); }
    short8 bf0[4], bf1[4];
#pragma unroll
    for (int nt = 0; nt < 4; nt++) {
      const unsigned short* bp = bbase + (size_t)(nt * 16 + l16) * D_IN + k0;
      bf0[nt] = *(const short8*)(bp);
      bf1[nt] = *(const short8*)(bp + 32);
    }
#pragma unroll
    for (int nt = 0; nt < 4; nt++)
      acc[nt] = __builtin_amdgcn_mfma_f32_16x16x32_bf16(af0, bf0[nt], acc[nt], 0, 0, 0);
#pragma unroll
    for (int nt = 0; nt < 4; nt++)
      acc[nt] = __builtin_amdgcn_mfma_f32_16x16x32_bf16(af1, bf1[nt], acc[nt], 0, 0, 0);
  }
#pragma unroll
  for (int r = 0; r < 4; r++) {
    int row = rowbase + quad * 4 + r;
    float sc = dinv[row];
#pragma unroll
    for (int nt = 0; nt < 4; nt++)
      xw1s[(size_t)row * D_HID + nt * 16 + l16] = f2bf(acc[nt][r] * sc);
  }
}

// ---------- agg1 + gemm2 fused; 8 gather streams per half-wave ----------
__global__ __launch_bounds__(256) void k_agg1(const unsigned* __restrict__ xw1s2,
    const int* __restrict__ rowptr, const int* __restrict__ csr_src,
    const float* __restrict__ dinv, const float* __restrict__ b1,
    const float* __restrict__ w2, unsigned short* __restrict__ xw2s) {
  __shared__ float w2s[D_HID * N_CLS];
  __shared__ float2 hbuf[4][32];
  for (int i = threadIdx.x; i < D_HID * N_CLS; i += 256) w2s[i] = w2[i];
  __syncthreads();
  int wave = threadIdx.x >> 6;
  int lane = threadIdx.x & 63;
  int h = lane >> 5, l = lane & 31;
  int node = blockIdx.x * 4 + wave;
  float dd = dinv[node];
  int beg = rowptr[node], end = rowptr[node + 1];
  float cx[8], cy[8];
#pragma unroll
  for (int j = 0; j < 8; j++) { cx[j] = 0.f; cy[j] = 0.f; }
  int e = beg + h;
  for (; e + 14 < end; e += 16) {
    int idx[8];
#pragma unroll
    for (int j = 0; j < 8; j++) idx[j] = csr_src[e + 2 * j];
#pragma unroll
    for (int j = 0; j < 8; j++) {
      float2 v = bf2f2(xw1s2[(size_t)idx[j] * 32 + l]);
      cx[j] += v.x; cy[j] += v.y;
    }
  }
  for (; e < end; e += 2) {
    float2 v = bf2f2(xw1s2[(size_t)csr_src[e] * 32 + l]);
    cx[0] += v.x; cy[0] += v.y;
  }
  float sx = ((cx[0] + cx[1]) + (cx[2] + cx[3])) + ((cx[4] + cx[5]) + (cx[6] + cx[7]));
  float sy = ((cy[0] + cy[1]) + (cy[2] + cy[3])) + ((cy[4] + cy[5]) + (cy[6] + cy[7]));
  sx += __shfl_down(sx, 32);
  sy += __shfl_down(sy, 32);
  if (lane < 32) {
    float2 self = bf2f2(xw1s2[(size_t)node * 32 + l]);
    float2 bb = ((const float2*)b1)[l];
    float vx = dd * (sx + self.x) + bb.x;
    float vy = dd * (sy + self.y) + bb.y;
    hbuf[wave][l] = make_float2(vx > 0.f ? vx : 0.f, vy > 0.f ? vy : 0.f);
  }
  __syncthreads();
  const float* hb = (const float*)hbuf[wave];
  int c = lane & 31;
  float p = 0.f;
#pragma unroll
  for (int kk = 0; kk < 32; kk++) {
    int k = h * 32 + kk;
    p += hb[k] * w2s[k * N_CLS + c];
  }
  p += __shfl_down(p, 32);
  if (lane < 32) xw2s[(size_t)node * N_CLS + c] = f2bf(p * dd);
}

// ---------- agg2 + log_softmax; 4 gather streams per quarter-wave ----------
__global__ __launch_bounds__(256) void k_agg2(const unsigned* __restrict__ xw2s2,
    const int* __restrict__ rowptr, const int* __restrict__ csr_src,
    const float* __restrict__ dinv, const float* __restrict__ b2,
    float* __restrict__ out) {
  int wave = threadIdx.x >> 6;
  int lane = threadIdx.x & 63;
  int q = lane >> 4, l = lane & 15;
  int node = blockIdx.x * 4 + wave;
  float dd = dinv[node];
  int beg = rowptr[node], end = rowptr[node + 1];
  float cx[4], cy[4];
#pragma unroll
  for (int j = 0; j < 4; j++) { cx[j] = 0.f; cy[j] = 0.f; }
  int e = beg + q;
  for (; e + 12 < end; e += 16) {
    int idx[4];
#pragma unroll
    for (int j = 0; j < 4; j++) idx[j] = csr_src[e + 4 * j];
#pragma unroll
    for (int j = 0; j < 4; j++) {
      float2 v = bf2f2(xw2s2[(size_t)idx[j] * 16 + l]);
      cx[j] += v.x; cy[j] += v.y;
    }
  }
  for (; e < end; e += 4) {
    float2 v = bf2f2(xw2s2[(size_t)csr_src[e] * 16 + l]);
    cx[0] += v.x; cy[0] += v.y;
  }
  float sx = (cx[0] + cx[1]) + (cx[2] + cx[3]);
  float sy = (cy[0] + cy[1]) + (cy[2] + cy[3]);
  sx += __shfl_down(sx, 32); sy += __shfl_down(sy, 32);
  sx += __shfl_down(sx, 16); sy += __shfl_down(sy, 16);
  if (lane < 16) {
    float2 self = bf2f2(xw2s2[(size_t)node * 16 + l]);
    float2 bb = ((const float2*)b2)[l];
    float lx = dd * (sx + self.x) + bb.x;
    float ly = dd * (sy + self.y) + bb.y;
    float m = fmaxf(lx, ly);
#pragma unroll
    for (int o = 8; o > 0; o >>= 1) m = fmaxf(m, __shfl_xor(m, o));
    float s2 = __expf(lx - m) + __expf(ly - m);
#pragma unroll
    for (int o = 8; o > 0; o >>= 1) s2 += __shfl_xor(s2, o);
    float lse = m + __logf(s2);
    ((float2*)out)[(size_t)node * 16 + l] = make_float2(lx - lse, ly - lse);
  }
}

extern "C" void kernel_launch(void* const* d_in, const int* in_sizes, int n_in,
                              void* d_out, int out_size, void* d_ws, size_t ws_size,
                              hipStream_t stream) {
  (void)n_in; (void)out_size; (void)ws_size;
  const float* x  = (const float*)d_in[0];
  const int*   ei = (const int*)d_in[1];
  const float* w1 = (const float*)d_in[2];
  const float* b1 = (const float*)d_in[3];
  const float* w2 = (const float*)d_in[4];
  const float* b2 = (const float*)d_in[5];
  float* out = (float*)d_out;
  int e = in_sizes[1] / 2;
  const int* src = ei;
  const int* dst = ei + e;

  char* ws = (char*)d_ws;
  int* cnt            = (int*)(ws + 0x000000);            // 256KB
  int* rowptr         = (int*)(ws + 0x040000);            // 256KB + 4
  int* cursor         = (int*)(ws + 0x0C0000);            // 256KB
  float* dinv         = (float*)(ws + 0x100000);          // 256KB
  int* bsum           = (int*)(ws + 0x140000);            // 1KB
  int* csr_src        = (int*)(ws + 0x180000);            // 4MB
  unsigned short* w1t = (unsigned short*)(ws + 0x580000); // 128KB
  unsigned short* xw1s= (unsigned short*)(ws + 0x600000); // 8MB (bf16)
  unsigned short* xw2s= (unsigned short*)(ws + 0xE00000); // 4MB (bf16)

  int e4 = e / 4;
  hipMemsetAsync(cnt, 0, N_NODES * sizeof(int), stream);
  k_count_w1t<<<1280, 256, 0, stream>>>(dst, cnt, w1, w1t, e4);
  k_scan_a   <<<N_NODES / 256, 256, 0, stream>>>(cnt, bsum);
  k_scan_c   <<<N_NODES / 256, 256, 0, stream>>>(cnt, bsum, rowptr, cursor, dinv);
  k_fill_gemm1<<<2048, 256, 0, stream>>>(src, dst, cursor, csr_src, e4,
                                         x, w1t, dinv, xw1s);
  k_agg1     <<<N_NODES / 4, 256, 0, stream>>>((const unsigned*)xw1s, rowptr, csr_src,
                                               dinv, b1, w2, xw2s);
  k_agg2     <<<N_NODES / 4, 256, 0, stream>>>((const unsigned*)xw2s, rowptr, csr_src,
                                               dinv, b2, out);
}